// Round 4
// baseline (791.796 us; speedup 1.0000x reference)
//
#include <hip/hip_runtime.h>

#define N_NODES   100000
#define N_EDGES   1600000
#define N_GRAPHS  256
#define D         32
#define GD        (N_GRAPHS * D)   // 8192
#define CAP       8192             // per-graph bucket capacity (mean 6250, ~24 sigma headroom)

// ---------------- pass 1: bucket edge ids by graph of their src node ----------------
__global__ __launch_bounds__(256) void scatter_kernel(
        const int* __restrict__ src,
        const int* __restrict__ batch,
        int* __restrict__ gcount,     // [256], zeroed each call
        int* __restrict__ bucket) {   // [256][CAP]
    const int e = blockIdx.x * blockDim.x + threadIdx.x;
    if (e >= N_EDGES) return;
    const int g = batch[src[e]];                 // batch (400KB) is L2/L3-resident
    const int pos = atomicAdd(&gcount[g], 1);    // int global atomic, 256 hot addrs
    if (pos < CAP) bucket[g * CAP + pos] = e;
}

// ---------------- pass 2: gather-reduce edge_attr rows per graph ----------------
// 8 blocks per graph. Thread layout: s = tid>>3 (row slot, 32), c = tid&7 (float4 col).
// Each edge row is 128B = exactly one cache line; 8 threads share it.
// Register accumulation -> LDS tree reduce -> 32 global f32 atomics per block.
__global__ __launch_bounds__(256) void edge_gather_kernel(
        const float* __restrict__ ea,
        const int* __restrict__ bucket,
        const int* __restrict__ gcount,
        float* __restrict__ eacc /* [256][32], zeroed each call */) {
    const int g = blockIdx.x >> 3;
    const int q = blockIdx.x & 7;
    const int n = min(gcount[g], CAP);
    const int s = threadIdx.x >> 3;
    const int c = threadIdx.x & 7;
    const float4* __restrict__ ea4 = (const float4*)ea;
    const int* __restrict__ bk = bucket + g * CAP;

    float4 a = make_float4(0.f, 0.f, 0.f, 0.f);
    int j = q * 32 + s;                      // 8 blocks x 32 slots = stride 256
    // 4-deep staged unroll: 4 independent bucket loads, then 4 independent row loads
    for (; j + 768 < n; j += 1024) {
        const int e0 = bk[j];
        const int e1 = bk[j + 256];
        const int e2 = bk[j + 512];
        const int e3 = bk[j + 768];
        const float4 v0 = ea4[e0 * 8 + c];
        const float4 v1 = ea4[e1 * 8 + c];
        const float4 v2 = ea4[e2 * 8 + c];
        const float4 v3 = ea4[e3 * 8 + c];
        a.x += v0.x + v1.x + v2.x + v3.x;
        a.y += v0.y + v1.y + v2.y + v3.y;
        a.z += v0.z + v1.z + v2.z + v3.z;
        a.w += v0.w + v1.w + v2.w + v3.w;
    }
    for (; j < n; j += 256) {
        const int e = bk[j];
        const float4 v = ea4[e * 8 + c];
        a.x += v.x; a.y += v.y; a.z += v.z; a.w += v.w;
    }

    __shared__ float4 red[256];
    red[threadIdx.x] = a;
    __syncthreads();
    if (threadIdx.x < 8) {
        float4 t = make_float4(0.f, 0.f, 0.f, 0.f);
        #pragma unroll
        for (int s2 = 0; s2 < 32; ++s2) {
            const float4 b = red[s2 * 8 + threadIdx.x];
            t.x += b.x; t.y += b.y; t.z += b.z; t.w += b.w;
        }
        float* dst = eacc + g * D + threadIdx.x * 4;
        unsafeAtomicAdd(dst + 0, t.x);
        unsafeAtomicAdd(dst + 1, t.y);
        unsafeAtomicAdd(dst + 2, t.z);
        unsafeAtomicAdd(dst + 3, t.w);
    }
}

// ---------------- pass 3: node ranges are contiguous (batch sorted) ----------------
__global__ __launch_bounds__(256) void node_gather_kernel(
        const float* __restrict__ x,
        const int* __restrict__ batch,
        float* __restrict__ nacc /* [256][32], zeroed each call */) {
    const int g = blockIdx.x >> 1;
    const int q = blockIdx.x & 1;
    // [r0, r1) = node range of graph g
    int lo = 0, hi = N_NODES;
    while (lo < hi) { const int m = (lo + hi) >> 1; if (batch[m] < g) lo = m + 1; else hi = m; }
    const int r0 = lo;
    hi = N_NODES;
    while (lo < hi) { const int m = (lo + hi) >> 1; if (batch[m] < g + 1) lo = m + 1; else hi = m; }
    const int r1 = lo;

    const int s = threadIdx.x >> 3;
    const int c = threadIdx.x & 7;
    const float4* __restrict__ x4 = (const float4*)x;

    float4 a = make_float4(0.f, 0.f, 0.f, 0.f);
    int r = r0 + q * 32 + s;                 // 2 blocks x 32 slots = stride 64
    for (; r + 64 < r1; r += 128) {
        const float4 v0 = x4[r * 8 + c];
        const float4 v1 = x4[(r + 64) * 8 + c];
        a.x += v0.x + v1.x;
        a.y += v0.y + v1.y;
        a.z += v0.z + v1.z;
        a.w += v0.w + v1.w;
    }
    for (; r < r1; r += 64) {
        const float4 v = x4[r * 8 + c];
        a.x += v.x; a.y += v.y; a.z += v.z; a.w += v.w;
    }

    __shared__ float4 red[256];
    red[threadIdx.x] = a;
    __syncthreads();
    if (threadIdx.x < 8) {
        float4 t = make_float4(0.f, 0.f, 0.f, 0.f);
        #pragma unroll
        for (int s2 = 0; s2 < 32; ++s2) {
            const float4 b = red[s2 * 8 + threadIdx.x];
            t.x += b.x; t.y += b.y; t.z += b.z; t.w += b.w;
        }
        float* dst = nacc + g * D + threadIdx.x * 4;
        unsafeAtomicAdd(dst + 0, t.x);
        unsafeAtomicAdd(dst + 1, t.y);
        unsafeAtomicAdd(dst + 2, t.z);
        unsafeAtomicAdd(dst + 3, t.w);
    }
}

// ---------------- MLP: out = relu([nacc|eacc|u] @ W + b) ----------------
__global__ void mlp_kernel(const float* __restrict__ acc, // node then edge
                           const float* __restrict__ u,
                           const float* __restrict__ W,   // [3D][D]
                           const float* __restrict__ bias,
                           float* __restrict__ out) {
    __shared__ float Ws[3 * D * D]; // 12 KB
    for (int i = threadIdx.x; i < 3 * D * D; i += blockDim.x) Ws[i] = W[i];
    __syncthreads();

    const int t = blockIdx.x * blockDim.x + threadIdx.x; // 8192 threads
    const int g = t >> 5;
    const int d = t & 31;
    const float* __restrict__ nacc = acc;
    const float* __restrict__ eacc = acc + GD;

    float s = bias[d];
    #pragma unroll
    for (int k = 0; k < D; ++k) s += nacc[g * D + k] * Ws[k * D + d];
    #pragma unroll
    for (int k = 0; k < D; ++k) s += eacc[g * D + k] * Ws[(D + k) * D + d];
    #pragma unroll
    for (int k = 0; k < D; ++k) s += u[g * D + k] * Ws[(2 * D + k) * D + d];
    out[t] = fmaxf(s, 0.f);
}

extern "C" void kernel_launch(void* const* d_in, const int* in_sizes, int n_in,
                              void* d_out, int out_size, void* d_ws, size_t ws_size,
                              hipStream_t stream) {
    const float* x     = (const float*)d_in[0];
    const int*   ei    = (const int*)  d_in[1];  // [2, N_EDGES]; row 0 = src
    const float* ea    = (const float*)d_in[2];
    const float* u     = (const float*)d_in[3];
    const int*   batch = (const int*)  d_in[4];
    const float* W     = (const float*)d_in[5];
    const float* bias  = (const float*)d_in[6];
    float*       out   = (float*)d_out;

    // ws layout: [gcount 256 i32][acc 2*GD f32][bucket 256*CAP i32] ~= 8.4 MB
    int*   gcount = (int*)d_ws;
    float* acc    = (float*)((char*)d_ws + 1024);            // nacc | eacc
    int*   bucket = (int*)((char*)d_ws + 1024 + 2 * GD * sizeof(float));

    // zero counters + accumulators every call (atomics accumulate into them)
    hipMemsetAsync(d_ws, 0, 1024 + 2 * GD * sizeof(float), stream);

    scatter_kernel<<<(N_EDGES + 255) / 256, 256, 0, stream>>>(ei, batch, gcount, bucket);
    node_gather_kernel<<<2 * N_GRAPHS, 256, 0, stream>>>(x, batch, acc);
    edge_gather_kernel<<<8 * N_GRAPHS, 256, 0, stream>>>(ea, bucket, gcount, acc + GD);
    mlp_kernel<<<GD / 256, 256, 0, stream>>>(acc, u, W, bias, out);
}

// Round 5
// 81.487 us; speedup vs baseline: 9.7169x; 9.7169x over previous
//
#include <hip/hip_runtime.h>

#define N_NODES   100000
#define N_EDGES   1600000
#define N_GRAPHS  256
#define D         32
#define GD        (N_GRAPHS * D)          // 8192
#define NB        256                     // histogram/scatter blocks
#define EB        ((N_EDGES + NB - 1) / NB)  // 6250 edges per block

// ---------- pass 1: per-block histogram of g = batch[src[e]] ----------
__global__ __launch_bounds__(1024) void hist_kernel(const int* __restrict__ src,
                                                    const int* __restrict__ batch,
                                                    int* __restrict__ hist /* [NB][256] */) {
    __shared__ int h[N_GRAPHS];
    for (int i = threadIdx.x; i < N_GRAPHS; i += 1024) h[i] = 0;
    __syncthreads();
    const int start = blockIdx.x * EB;
    const int end   = min(start + EB, N_EDGES);
    for (int e = start + (int)threadIdx.x; e < end; e += 1024)
        atomicAdd(&h[batch[src[e]]], 1);          // LDS ds_add_u32, no return
    __syncthreads();
    for (int i = threadIdx.x; i < N_GRAPHS; i += 1024)
        hist[blockIdx.x * N_GRAPHS + i] = h[i];
}

// ---------- pass 2: column-wise exclusive prefix over blocks (in place) ----------
__global__ void prefix_kernel(int* __restrict__ hist, int* __restrict__ gcount) {
    const int g = threadIdx.x;                    // 256 threads, 1 block
    int run = 0;
    for (int b = 0; b < NB; ++b) {
        const int t = hist[b * N_GRAPHS + g];     // coalesced across g
        hist[b * N_GRAPHS + g] = run;             // now the per-block base
        run += t;
    }
    gcount[g] = run;
}

// ---------- pass 3: scatter edge ids into per-graph buckets ----------
__global__ __launch_bounds__(1024) void scatter_kernel(const int* __restrict__ src,
                                                       const int* __restrict__ batch,
                                                       const int* __restrict__ base /* [NB][256] */,
                                                       int cap,
                                                       int* __restrict__ bucket /* [256][cap] */) {
    __shared__ int cur[N_GRAPHS];
    for (int i = threadIdx.x; i < N_GRAPHS; i += 1024)
        cur[i] = base[blockIdx.x * N_GRAPHS + i];
    __syncthreads();
    const int start = blockIdx.x * EB;
    const int end   = min(start + EB, N_EDGES);
    for (int e = start + (int)threadIdx.x; e < end; e += 1024) {
        const int g   = batch[src[e]];
        const int pos = atomicAdd(&cur[g], 1);    // LDS rank, cheap
        if (pos < cap) bucket[g * cap + pos] = e;
    }
}

// ---------- node partials: batch sorted -> contiguous ranges, plain stores ----------
__global__ __launch_bounds__(256) void node_gather_kernel(
        const float* __restrict__ x,
        const int* __restrict__ batch,
        float* __restrict__ npart /* [2][256][32] */) {
    const int g = blockIdx.x >> 1;
    const int q = blockIdx.x & 1;
    int lo = 0, hi = N_NODES;
    while (lo < hi) { const int m = (lo + hi) >> 1; if (batch[m] < g) lo = m + 1; else hi = m; }
    const int r0 = lo;
    hi = N_NODES;
    while (lo < hi) { const int m = (lo + hi) >> 1; if (batch[m] < g + 1) lo = m + 1; else hi = m; }
    const int r1 = lo;

    const int s = threadIdx.x >> 3;
    const int c = threadIdx.x & 7;
    const float4* __restrict__ x4 = (const float4*)x;

    float4 a = make_float4(0.f, 0.f, 0.f, 0.f);
    int r = r0 + q * 32 + s;                      // 2 blocks x 32 slots = stride 64
    for (; r + 64 < r1; r += 128) {
        const float4 v0 = x4[r * 8 + c];
        const float4 v1 = x4[(r + 64) * 8 + c];
        a.x += v0.x + v1.x; a.y += v0.y + v1.y;
        a.z += v0.z + v1.z; a.w += v0.w + v1.w;
    }
    for (; r < r1; r += 64) {
        const float4 v = x4[r * 8 + c];
        a.x += v.x; a.y += v.y; a.z += v.z; a.w += v.w;
    }

    __shared__ float4 red[256];
    red[threadIdx.x] = a;
    __syncthreads();
    if (threadIdx.x < 8) {
        float4 t = make_float4(0.f, 0.f, 0.f, 0.f);
        #pragma unroll
        for (int s2 = 0; s2 < 32; ++s2) {
            const float4 b = red[s2 * 8 + threadIdx.x];
            t.x += b.x; t.y += b.y; t.z += b.z; t.w += b.w;
        }
        ((float4*)(npart + (size_t)(q * N_GRAPHS + g) * D))[threadIdx.x] = t;
    }
}

// ---------- edge partials: gather bucketed rows, plain stores ----------
__global__ __launch_bounds__(256) void edge_gather_kernel(
        const float* __restrict__ ea,
        const int* __restrict__ bucket,
        const int* __restrict__ gcount,
        int cap,
        float* __restrict__ epart /* [8][256][32] */) {
    const int g = blockIdx.x >> 3;
    const int q = blockIdx.x & 7;
    const int n = min(gcount[g], cap);
    const int s = threadIdx.x >> 3;
    const int c = threadIdx.x & 7;
    const float4* __restrict__ ea4 = (const float4*)ea;
    const int* __restrict__ bk = bucket + (size_t)g * cap;

    float4 a = make_float4(0.f, 0.f, 0.f, 0.f);
    int j = q * 32 + s;                           // 8 blocks x 32 slots = stride 256
    for (; j + 768 < n; j += 1024) {              // 4 independent id loads, then 4 row loads
        const int e0 = bk[j];
        const int e1 = bk[j + 256];
        const int e2 = bk[j + 512];
        const int e3 = bk[j + 768];
        const float4 v0 = ea4[e0 * 8 + c];
        const float4 v1 = ea4[e1 * 8 + c];
        const float4 v2 = ea4[e2 * 8 + c];
        const float4 v3 = ea4[e3 * 8 + c];
        a.x += v0.x + v1.x + v2.x + v3.x;
        a.y += v0.y + v1.y + v2.y + v3.y;
        a.z += v0.z + v1.z + v2.z + v3.z;
        a.w += v0.w + v1.w + v2.w + v3.w;
    }
    for (; j < n; j += 256) {
        const float4 v = ea4[bk[j] * 8 + c];
        a.x += v.x; a.y += v.y; a.z += v.z; a.w += v.w;
    }

    __shared__ float4 red[256];
    red[threadIdx.x] = a;
    __syncthreads();
    if (threadIdx.x < 8) {
        float4 t = make_float4(0.f, 0.f, 0.f, 0.f);
        #pragma unroll
        for (int s2 = 0; s2 < 32; ++s2) {
            const float4 b = red[s2 * 8 + threadIdx.x];
            t.x += b.x; t.y += b.y; t.z += b.z; t.w += b.w;
        }
        ((float4*)(epart + (size_t)(q * N_GRAPHS + g) * D))[threadIdx.x] = t;
    }
}

// ---------- MLP: out = relu([Σnpart | Σepart | u] @ W + b), 8 graphs/block ----------
__global__ __launch_bounds__(256) void mlp_kernel(const float* __restrict__ npart,
                                                  const float* __restrict__ epart,
                                                  const float* __restrict__ u,
                                                  const float* __restrict__ W,   // [3D][D]
                                                  const float* __restrict__ bias,
                                                  float* __restrict__ out) {
    __shared__ float Ws[3 * D * D];               // 12 KB
    __shared__ float accN[8][D];
    __shared__ float accE[8][D];
    for (int i = threadIdx.x; i < 3 * D * D; i += 256) Ws[i] = W[i];

    const int gl = threadIdx.x >> 5;              // graph within block, 0..7
    const int k  = threadIdx.x & 31;
    const int g  = blockIdx.x * 8 + gl;

    float sn = 0.f, se = 0.f;
    #pragma unroll
    for (int q = 0; q < 2; ++q) sn += npart[(size_t)(q * N_GRAPHS + g) * D + k];
    #pragma unroll
    for (int q = 0; q < 8; ++q) se += epart[(size_t)(q * N_GRAPHS + g) * D + k];
    accN[gl][k] = sn;
    accE[gl][k] = se;
    __syncthreads();

    const int d = k;
    float s = bias[d];
    const float* __restrict__ ug = u + g * D;
    #pragma unroll
    for (int kk = 0; kk < D; ++kk) s += accN[gl][kk] * Ws[kk * D + d];
    #pragma unroll
    for (int kk = 0; kk < D; ++kk) s += accE[gl][kk] * Ws[(D + kk) * D + d];
    #pragma unroll
    for (int kk = 0; kk < D; ++kk) s += ug[kk] * Ws[(2 * D + kk) * D + d];
    out[g * D + d] = fmaxf(s, 0.f);
}

extern "C" void kernel_launch(void* const* d_in, const int* in_sizes, int n_in,
                              void* d_out, int out_size, void* d_ws, size_t ws_size,
                              hipStream_t stream) {
    const float* x     = (const float*)d_in[0];
    const int*   ei    = (const int*)  d_in[1];   // [2][N_EDGES]; row 0 = src
    const float* ea    = (const float*)d_in[2];
    const float* u     = (const float*)d_in[3];
    const int*   batch = (const int*)  d_in[4];
    const float* W     = (const float*)d_in[5];
    const float* bias  = (const float*)d_in[6];
    float*       out   = (float*)d_out;

    // ws: [hist NB*256 i32][gcount 256 i32][npart 2*GD f32][epart 8*GD f32][bucket 256*cap i32]
    int*   hist   = (int*)d_ws;
    int*   gcount = hist + NB * N_GRAPHS;
    float* npart  = (float*)(gcount + N_GRAPHS);
    float* epart  = npart + 2 * GD;
    int*   bucket = (int*)(epart + 8 * GD);
    const size_t fixed = (size_t)((char*)bucket - (char*)d_ws);
    int cap = (int)((ws_size - fixed) / (N_GRAPHS * sizeof(int)));
    if (cap > 8192) cap = 8192;                   // mean 6250, sigma ~79 -> huge headroom

    hist_kernel   <<<NB, 1024, 0, stream>>>(ei, batch, hist);
    prefix_kernel <<<1, N_GRAPHS, 0, stream>>>(hist, gcount);
    scatter_kernel<<<NB, 1024, 0, stream>>>(ei, batch, hist, cap, bucket);
    node_gather_kernel<<<2 * N_GRAPHS, 256, 0, stream>>>(x, batch, npart);
    edge_gather_kernel<<<8 * N_GRAPHS, 256, 0, stream>>>(ea, bucket, gcount, cap, epart);
    mlp_kernel    <<<N_GRAPHS / 8, 256, 0, stream>>>(npart, epart, u, W, bias, out);
}

// Round 6
// 78.980 us; speedup vs baseline: 10.0253x; 1.0317x over previous
//
#include <hip/hip_runtime.h>

#define N_NODES   100000
#define N_EDGES   1600000
#define N_GRAPHS  256
#define D         32
#define GD        (N_GRAPHS * D)   // 8192
#define LSTRIDE   257              // lds[d*257+g]: 257 % 32 == 1 -> bank (d*... + g + k) spreads
#define NBLK      512              // edge_stream blocks
#define SCALE_F   1048576.0f       // 2^20 fixed-point scale
#define INV_SCALE 9.5367431640625e-07f

// ---------- pass A: g8[e] = (u8) batch[src[e]] ----------
__global__ __launch_bounds__(1024) void g8_kernel(const int* __restrict__ src,
                                                  const int* __restrict__ batch,
                                                  unsigned char* __restrict__ g8) {
    const int stride = gridDim.x * blockDim.x;
    int i = blockIdx.x * blockDim.x + threadIdx.x;
    for (; i + 3 * stride < N_EDGES; i += 4 * stride) {
        const int s0 = src[i];
        const int s1 = src[i + stride];
        const int s2 = src[i + 2 * stride];
        const int s3 = src[i + 3 * stride];
        const int b0 = batch[s0], b1 = batch[s1], b2 = batch[s2], b3 = batch[s3];
        g8[i]              = (unsigned char)b0;
        g8[i + stride]     = (unsigned char)b1;
        g8[i + 2 * stride] = (unsigned char)b2;
        g8[i + 3 * stride] = (unsigned char)b3;
    }
    for (; i < N_EDGES; i += stride) g8[i] = (unsigned char)batch[src[i]];
}

// ---------- edge aggregation: stream ea, int fixed-point LDS accumulate ----------
// Depth-1 rotating pipeline: next iteration's loads are issued BEFORE this
// iteration's LDS adds, so HBM latency overlaps the atomic work by construction.
__global__ __launch_bounds__(1024) void edge_stream_kernel(
        const float* __restrict__ ea,
        const unsigned char* __restrict__ g8,
        int* __restrict__ epart /* [NBLK][GD], (g,d)-major */) {
    __shared__ int lds[D * LSTRIDE];               // 32.9 KB
    for (int i = threadIdx.x; i < D * LSTRIDE; i += 1024) lds[i] = 0;
    __syncthreads();

    const float4* __restrict__ ea4 = (const float4*)ea;
    const int total  = N_EDGES * (D / 4);          // 12.8M float4 units
    const int stride = gridDim.x * blockDim.x;

    int icur = blockIdx.x * blockDim.x + threadIdx.x;
    bool have = icur < total;
    float4 v = make_float4(0.f, 0.f, 0.f, 0.f);
    int g = 0;
    if (have) { v = ea4[icur]; g = g8[icur >> 3]; }

    while (have) {
        const int inext = icur + stride;
        const bool haven = inext < total;
        float4 vn = make_float4(0.f, 0.f, 0.f, 0.f);
        int gn = 0;
        if (haven) { vn = ea4[inext]; gn = g8[inext >> 3]; }  // issued before adds

        const int base = ((icur & 7) * 4) * LSTRIDE + g;
        atomicAdd(&lds[base              ], __float2int_rn(v.x * SCALE_F));
        atomicAdd(&lds[base +     LSTRIDE], __float2int_rn(v.y * SCALE_F));
        atomicAdd(&lds[base + 2 * LSTRIDE], __float2int_rn(v.z * SCALE_F));
        atomicAdd(&lds[base + 3 * LSTRIDE], __float2int_rn(v.w * SCALE_F));

        icur = inext; v = vn; g = gn; have = haven;
    }
    __syncthreads();

    int* __restrict__ my = epart + (size_t)blockIdx.x * GD;
    for (int i = threadIdx.x; i < GD; i += 1024) {
        const int gg = i >> 5;
        const int d  = i & 31;
        my[i] = lds[d * LSTRIDE + gg];             // conflict-free, coalesced store
    }
}

// ---------- node partials: batch sorted -> contiguous ranges, plain stores ----------
__global__ __launch_bounds__(256) void node_gather_kernel(
        const float* __restrict__ x,
        const int* __restrict__ batch,
        float* __restrict__ npart /* [2][256][32] */) {
    const int g = blockIdx.x >> 1;
    const int q = blockIdx.x & 1;
    int lo = 0, hi = N_NODES;
    while (lo < hi) { const int m = (lo + hi) >> 1; if (batch[m] < g) lo = m + 1; else hi = m; }
    const int r0 = lo;
    hi = N_NODES;
    while (lo < hi) { const int m = (lo + hi) >> 1; if (batch[m] < g + 1) lo = m + 1; else hi = m; }
    const int r1 = lo;

    const int s = threadIdx.x >> 3;
    const int c = threadIdx.x & 7;
    const float4* __restrict__ x4 = (const float4*)x;

    float4 a = make_float4(0.f, 0.f, 0.f, 0.f);
    int r = r0 + q * 32 + s;                       // 2 blocks x 32 slots = stride 64
    for (; r + 64 < r1; r += 128) {
        const float4 v0 = x4[r * 8 + c];
        const float4 v1 = x4[(r + 64) * 8 + c];
        a.x += v0.x + v1.x; a.y += v0.y + v1.y;
        a.z += v0.z + v1.z; a.w += v0.w + v1.w;
    }
    for (; r < r1; r += 64) {
        const float4 v = x4[r * 8 + c];
        a.x += v.x; a.y += v.y; a.z += v.z; a.w += v.w;
    }

    __shared__ float4 red[256];
    red[threadIdx.x] = a;
    __syncthreads();
    if (threadIdx.x < 8) {
        float4 t = make_float4(0.f, 0.f, 0.f, 0.f);
        #pragma unroll
        for (int s2 = 0; s2 < 32; ++s2) {
            const float4 b = red[s2 * 8 + threadIdx.x];
            t.x += b.x; t.y += b.y; t.z += b.z; t.w += b.w;
        }
        ((float4*)(npart + (size_t)(q * N_GRAPHS + g) * D))[threadIdx.x] = t;
    }
}

// ---------- reduce: acc[0:GD) = sum npart (float); acc[GD:2GD) = sum epart (int->float) ----------
__global__ __launch_bounds__(256) void reduce_kernel(const float* __restrict__ npart,
                                                     const int* __restrict__ epart,
                                                     float* __restrict__ acc) {
    const int t = blockIdx.x * blockDim.x + threadIdx.x;   // 2*GD threads
    if (t < GD) {
        acc[t] = npart[t] + npart[GD + t];
    } else {
        const int c = t - GD;
        int s = 0;                                 // exact int sum; |total| << 2^31
        #pragma unroll 8
        for (int p = 0; p < NBLK; ++p) s += epart[(size_t)p * GD + c];
        acc[t] = (float)s * INV_SCALE;
    }
}

// ---------- MLP: out = relu([nacc|eacc|u] @ W + b), 8 graphs/block ----------
__global__ __launch_bounds__(256) void mlp_kernel(const float* __restrict__ acc,
                                                  const float* __restrict__ u,
                                                  const float* __restrict__ W,   // [3D][D]
                                                  const float* __restrict__ bias,
                                                  float* __restrict__ out) {
    __shared__ float Ws[3 * D * D];                // 12 KB
    __shared__ float accN[8][D];
    __shared__ float accE[8][D];
    for (int i = threadIdx.x; i < 3 * D * D; i += 256) Ws[i] = W[i];

    const int gl = threadIdx.x >> 5;               // graph within block, 0..7
    const int k  = threadIdx.x & 31;
    const int g  = blockIdx.x * 8 + gl;

    accN[gl][k] = acc[g * D + k];
    accE[gl][k] = acc[GD + g * D + k];
    __syncthreads();

    const int d = k;
    float s = bias[d];
    const float* __restrict__ ug = u + g * D;
    #pragma unroll
    for (int kk = 0; kk < D; ++kk) s += accN[gl][kk] * Ws[kk * D + d];
    #pragma unroll
    for (int kk = 0; kk < D; ++kk) s += accE[gl][kk] * Ws[(D + kk) * D + d];
    #pragma unroll
    for (int kk = 0; kk < D; ++kk) s += ug[kk] * Ws[(2 * D + kk) * D + d];
    out[g * D + d] = fmaxf(s, 0.f);
}

extern "C" void kernel_launch(void* const* d_in, const int* in_sizes, int n_in,
                              void* d_out, int out_size, void* d_ws, size_t ws_size,
                              hipStream_t stream) {
    const float* x     = (const float*)d_in[0];
    const int*   ei    = (const int*)  d_in[1];    // [2][N_EDGES]; row 0 = src
    const float* ea    = (const float*)d_in[2];
    const float* u     = (const float*)d_in[3];
    const int*   batch = (const int*)  d_in[4];
    const float* W     = (const float*)d_in[5];
    const float* bias  = (const float*)d_in[6];
    float*       out   = (float*)d_out;

    // ws: [g8 1.6MB pad][npart 2*GD f32][epart NBLK*GD i32][acc 2*GD f32] ~= 18 MB
    const size_t g8_bytes = (size_t)((N_EDGES + 255) & ~255);
    unsigned char* g8    = (unsigned char*)d_ws;
    float*         npart = (float*)((char*)d_ws + g8_bytes);
    int*           epart = (int*)(npart + 2 * GD);
    float*         acc   = (float*)(epart + (size_t)NBLK * GD);

    g8_kernel         <<<256, 1024, 0, stream>>>(ei, batch, g8);
    node_gather_kernel<<<2 * N_GRAPHS, 256, 0, stream>>>(x, batch, npart);
    edge_stream_kernel<<<NBLK, 1024, 0, stream>>>(ea, g8, epart);
    reduce_kernel     <<<(2 * GD) / 256, 256, 0, stream>>>(npart, epart, acc);
    mlp_kernel        <<<N_GRAPHS / 8, 256, 0, stream>>>(acc, u, W, bias, out);
}

// Round 7
// 65.324 us; speedup vs baseline: 12.1211x; 1.2090x over previous
//
#include <hip/hip_runtime.h>

#define N_NODES   100000
#define N_EDGES   1600000
#define N_GRAPHS  256
#define D         32
#define GD        (N_GRAPHS * D)   // 8192
#define LSTRIDE   257              // lds[d*257+g]: banks (d+g)%32 spread
#define NBLK      512              // edge_stream blocks
#define NBG       256              // g8 sub-blocks inside pre_kernel
#define SCALE_F   1048576.0f       // 2^20 fixed-point scale
#define INV_SCALE 9.5367431640625e-07f

// ---------- pre: blocks [0,256) compute g8; blocks [256,512) node partials ----------
__global__ __launch_bounds__(1024) void pre_kernel(
        const int* __restrict__ src,
        const int* __restrict__ batch,
        unsigned char* __restrict__ g8,
        const float* __restrict__ x,
        float* __restrict__ npart /* [256][32] */) {
    if (blockIdx.x < NBG) {
        // ---- g8[e] = (u8) batch[src[e]] ----
        const int stride = NBG * 1024;
        int i = blockIdx.x * 1024 + threadIdx.x;
        for (; i + 3 * stride < N_EDGES; i += 4 * stride) {
            const int s0 = src[i];
            const int s1 = src[i + stride];
            const int s2 = src[i + 2 * stride];
            const int s3 = src[i + 3 * stride];
            const int b0 = batch[s0], b1 = batch[s1], b2 = batch[s2], b3 = batch[s3];
            g8[i]              = (unsigned char)b0;
            g8[i + stride]     = (unsigned char)b1;
            g8[i + 2 * stride] = (unsigned char)b2;
            g8[i + 3 * stride] = (unsigned char)b3;
        }
        for (; i < N_EDGES; i += stride) g8[i] = (unsigned char)batch[src[i]];
        return;
    }

    // ---- node partial for graph g (batch sorted -> contiguous range) ----
    const int g = blockIdx.x - NBG;
    int lo = 0, hi = N_NODES;
    while (lo < hi) { const int m = (lo + hi) >> 1; if (batch[m] < g) lo = m + 1; else hi = m; }
    const int r0 = lo;
    hi = N_NODES;
    while (lo < hi) { const int m = (lo + hi) >> 1; if (batch[m] < g + 1) lo = m + 1; else hi = m; }
    const int r1 = lo;

    const int s = threadIdx.x >> 3;      // 0..127 row slots
    const int c = threadIdx.x & 7;       // float4 column
    const float4* __restrict__ x4 = (const float4*)x;

    float4 a = make_float4(0.f, 0.f, 0.f, 0.f);
    for (int r = r0 + s; r < r1; r += 128) {
        const float4 v = x4[r * 8 + c];
        a.x += v.x; a.y += v.y; a.z += v.z; a.w += v.w;
    }

    __shared__ float4 red[1024];         // 16 KB
    red[threadIdx.x] = a;
    __syncthreads();
    if (threadIdx.x < 256) {
        float4 t = red[threadIdx.x];
        const float4 b1 = red[threadIdx.x + 256];
        const float4 b2 = red[threadIdx.x + 512];
        const float4 b3 = red[threadIdx.x + 768];
        t.x += b1.x + b2.x + b3.x; t.y += b1.y + b2.y + b3.y;
        t.z += b1.z + b2.z + b3.z; t.w += b1.w + b2.w + b3.w;
        red[threadIdx.x] = t;
    }
    __syncthreads();
    if (threadIdx.x < 8) {
        float4 t = make_float4(0.f, 0.f, 0.f, 0.f);
        #pragma unroll
        for (int s2 = 0; s2 < 32; ++s2) {
            const float4 b = red[s2 * 8 + threadIdx.x];
            t.x += b.x; t.y += b.y; t.z += b.z; t.w += b.w;
        }
        ((float4*)(npart + (size_t)g * D))[threadIdx.x] = t;
    }
}

// ---------- edge aggregation: stream ea, int fixed-point LDS accumulate ----------
// Depth-1 rotating pipeline: next iteration's loads issue BEFORE this
// iteration's LDS adds, so HBM latency overlaps the atomic work.
__global__ __launch_bounds__(1024) void edge_stream_kernel(
        const float* __restrict__ ea,
        const unsigned char* __restrict__ g8,
        int* __restrict__ epart /* [NBLK][GD], (g,d)-major */) {
    __shared__ int lds[D * LSTRIDE];               // 32.9 KB
    for (int i = threadIdx.x; i < D * LSTRIDE; i += 1024) lds[i] = 0;
    __syncthreads();

    const float4* __restrict__ ea4 = (const float4*)ea;
    const int total  = N_EDGES * (D / 4);          // 12.8M float4 units
    const int stride = gridDim.x * blockDim.x;

    int icur = blockIdx.x * blockDim.x + threadIdx.x;
    bool have = icur < total;
    float4 v = make_float4(0.f, 0.f, 0.f, 0.f);
    int g = 0;
    if (have) { v = ea4[icur]; g = g8[icur >> 3]; }

    while (have) {
        const int inext = icur + stride;
        const bool haven = inext < total;
        float4 vn = make_float4(0.f, 0.f, 0.f, 0.f);
        int gn = 0;
        if (haven) { vn = ea4[inext]; gn = g8[inext >> 3]; }  // issued before adds

        const int base = ((icur & 7) * 4) * LSTRIDE + g;
        atomicAdd(&lds[base              ], __float2int_rn(v.x * SCALE_F));
        atomicAdd(&lds[base +     LSTRIDE], __float2int_rn(v.y * SCALE_F));
        atomicAdd(&lds[base + 2 * LSTRIDE], __float2int_rn(v.z * SCALE_F));
        atomicAdd(&lds[base + 3 * LSTRIDE], __float2int_rn(v.w * SCALE_F));

        icur = inext; v = vn; g = gn; have = haven;
    }
    __syncthreads();

    int* __restrict__ my = epart + (size_t)blockIdx.x * GD;
    for (int i = threadIdx.x; i < GD; i += 1024) {
        const int gg = i >> 5;
        const int d  = i & 31;
        my[i] = lds[d * LSTRIDE + gg];             // conflict-free, coalesced store
    }
}

// ---------- finish: per-graph column-sum of epart + npart, then MLP ----------
__global__ __launch_bounds__(256) void finish_kernel(
        const float* __restrict__ npart,  // [256][32]
        const int* __restrict__ epart,    // [NBLK][GD]
        const float* __restrict__ u,
        const float* __restrict__ W,      // [3D][D]
        const float* __restrict__ bias,
        float* __restrict__ out) {
    const int g = blockIdx.x;
    __shared__ float Ws[3 * D * D];                // 12 KB
    __shared__ int   ered[8][D];
    __shared__ float accN[D], accE[D], ush[D];

    for (int i = threadIdx.x; i < 3 * D * D; i += 256) Ws[i] = W[i];

    const int d  = threadIdx.x & 31;
    const int pg = threadIdx.x >> 5;               // 8 partial-groups
    int s = 0;
    for (int p = pg; p < NBLK; p += 8)             // 64 independent coalesced loads
        s += epart[(size_t)p * GD + g * D + d];
    ered[pg][d] = s;
    __syncthreads();

    if (threadIdx.x < D) {
        int tot = 0;
        #pragma unroll
        for (int q = 0; q < 8; ++q) tot += ered[q][threadIdx.x];
        accE[threadIdx.x] = (float)tot * INV_SCALE;
        accN[threadIdx.x] = npart[g * D + threadIdx.x];
        ush [threadIdx.x] = u[g * D + threadIdx.x];
    }
    __syncthreads();

    if (threadIdx.x < D) {
        float sacc = bias[threadIdx.x];
        #pragma unroll
        for (int kk = 0; kk < D; ++kk) sacc += accN[kk] * Ws[kk * D + threadIdx.x];
        #pragma unroll
        for (int kk = 0; kk < D; ++kk) sacc += accE[kk] * Ws[(D + kk) * D + threadIdx.x];
        #pragma unroll
        for (int kk = 0; kk < D; ++kk) sacc += ush[kk] * Ws[(2 * D + kk) * D + threadIdx.x];
        out[g * D + threadIdx.x] = fmaxf(sacc, 0.f);
    }
}

extern "C" void kernel_launch(void* const* d_in, const int* in_sizes, int n_in,
                              void* d_out, int out_size, void* d_ws, size_t ws_size,
                              hipStream_t stream) {
    const float* x     = (const float*)d_in[0];
    const int*   ei    = (const int*)  d_in[1];    // [2][N_EDGES]; row 0 = src
    const float* ea    = (const float*)d_in[2];
    const float* u     = (const float*)d_in[3];
    const int*   batch = (const int*)  d_in[4];
    const float* W     = (const float*)d_in[5];
    const float* bias  = (const float*)d_in[6];
    float*       out   = (float*)d_out;

    // ws: [g8 1.6MB pad][npart GD f32][epart NBLK*GD i32] ~= 18.4 MB
    const size_t g8_bytes = (size_t)((N_EDGES + 255) & ~255);
    unsigned char* g8    = (unsigned char*)d_ws;
    float*         npart = (float*)((char*)d_ws + g8_bytes);
    int*           epart = (int*)(npart + GD);

    pre_kernel        <<<NBG + N_GRAPHS, 1024, 0, stream>>>(ei, batch, g8, x, npart);
    edge_stream_kernel<<<NBLK, 1024, 0, stream>>>(ea, g8, epart);
    finish_kernel     <<<N_GRAPHS, 256, 0, stream>>>(npart, epart, u, W, bias, out);
}